// Round 8
// baseline (254.885 us; speedup 1.0000x reference)
//
#include <hip/hip_runtime.h>
#include <math.h>

// EquiTritonModel: N=10000 nodes, E=160000 edges, D=32, H=16, NB=16.
// R7 -> R8 (gather issue-bound: VALUBusy 25%, occ 27%):
//  - T0/T1 interleaved as float2 TI[a][j][2t+{0,1}]: j-loop issues 1 dwordx2
//    + 1 shfl + 2 adjacent fma per j (vs 2 loads + 1 shfl + 2 fma) -> half
//    the VMEM instructions in the hot loop, pk_fma-fusable.
//  - gather uses 64-thread blocks (1 wave = 1 node, grid = N): zero LDS
//    (G1T/G4T columns live in 16 regs/lane, reduce = wave shuffle, no
//    syncthreads), no tail predication, 10000 single-wave blocks for smooth
//    residency.

namespace {
constexpr int   NATOMS   = 100;
constexpr int   CAP      = 64;
constexpr float PI_F     = 3.14159265358979323846f;
constexpr float INV4PI_F = 0.28209479177387814f;   // 1/sqrt(4*pi)
constexpr float SQRT3_F  = 1.7320508075688772f;
constexpr float CUT_F    = 6.0f;
constexpr float BASIS_C  = 2.3094010767585034f;    // sqrt(2/6)*sqrt(16)
constexpr float N0_F     = 0.17677669529663687f;   // 1/sqrt(32)
constexpr float K0_F = INV4PI_F * N0_F * 0.0625f;
constexpr float K1_F = SQRT3_F * INV4PI_F * N0_F * 0.0625f;
}

__device__ __forceinline__ float silu_fast(float x) {
  return x / (1.0f + __expf(-x));
}

__device__ __forceinline__ float block_reduce_sum(float v) {
  #pragma unroll
  for (int o = 32; o > 0; o >>= 1) v += __shfl_down(v, o, 64);
  __shared__ float ls[8];
  int lane = threadIdx.x & 63;
  int w    = threadIdx.x >> 6;
  if (lane == 0) ls[w] = v;
  __syncthreads();
  float s = 0.f;
  if (threadIdx.x == 0) {
    int nw = (blockDim.x + 63) >> 6;
    for (int i = 0; i < nw; ++i) s += ls[i];
  }
  return s;
}

// ---------------------------------------------------------------------------
// Fused setup: blocks [0, NATOMS] precompute TI (float2-interleaved T0/T1)
// and G1T/G4T (transposed); blocks > NATOMS bucket edges by dst.
// ---------------------------------------------------------------------------
__global__ void setup_kernel(const float* __restrict__ atom_emb,
                             const float* __restrict__ fc0_w2,
                             const float* __restrict__ fc1_w2,
                             const float* __restrict__ w_readout,
                             const int* __restrict__ ei,
                             float* __restrict__ TI,
                             float* __restrict__ G1T, float* __restrict__ G4T,
                             int* __restrict__ cursor, int* __restrict__ elist,
                             int E) {
  int b = blockIdx.x;
  int tt = threadIdx.x;
  if (b < NATOMS) {
    int j = tt >> 4;    // hidden (h0) index
    int h = tt & 15;    // H-component
    float s0 = 0.f, s1 = 0.f;
    #pragma unroll
    for (int d = 0; d < 32; ++d) {
      float x = atom_emb[b * 32 + d];
      s0 = fmaf(x, fc0_w2[j * 1024 + d * 16 + h], s0);
      s1 = fmaf(x, fc0_w2[j * 1024 + 512 + d * 16 + h], s1);
    }
    TI[b * 512 + j * 32 + 2 * h]     = s0;  // lane h reads float2 at j*16+h
    TI[b * 512 + j * 32 + 2 * h + 1] = s1;
  } else if (b == NATOMS) {
    int j = tt >> 4;    // hidden (h1) index
    int h = tt & 15;    // H-component
    float g1 = 0.f, g4 = 0.f;
    #pragma unroll
    for (int k = 0; k < 16; ++k) {
      float r = w_readout[k];
      g1 = fmaf(fc1_w2[j * 1024 + h * 16 + k], r, g1);
      g4 = fmaf(fc1_w2[j * 1024 + 768 + h * 16 + k], r, g4);
    }
    G1T[h * 16 + j] = g1;    // [comp][hidden]: column t = lane-consecutive
    G4T[h * 16 + j] = g4;
  } else {
    int e = (b - NATOMS - 1) * blockDim.x + tt;
    if (e < E) {
      int d = ei[E + e];
      int pos = atomicAdd(&cursor[d], 1);
      if (pos < CAP) elist[d * CAP + pos] = ei[e];
    }
  }
}

// ---------------------------------------------------------------------------
// Phase 1: 64-thread blocks, one wave per node (grid = N). 4 groups x 16
// lanes; each group pipelines two edges (i, i+4). Lane t owns component t.
// No LDS: G column is register-resident. Epilogue: group 0 -> Q (G1),
// groups 1..3 -> Px/Py/Pz (G4); zbuf[node*64 + t*4 + g].
// ---------------------------------------------------------------------------
__global__ void __launch_bounds__(64)
gather_kernel(const int* __restrict__ elist,
              const int* __restrict__ cursor,
              const float* __restrict__ coords,
              const int* __restrict__ an,
              const float* __restrict__ fc0_w1,
              const float* __restrict__ TI,
              const float* __restrict__ G1T,
              const float* __restrict__ G4T,
              const float* __restrict__ w_readout,
              float* __restrict__ zbuf,
              float* __restrict__ out,
              int N) {
  int lane = threadIdx.x;        // 0..63
  int g    = lane >> 4;
  int t    = lane & 15;
  int base = lane & 48;
  int node = blockIdx.x;

  // register-resident tables
  float w0c[16], gcol[16];
  const float* gp = (g == 0) ? G1T : G4T;
  #pragma unroll
  for (int k = 0; k < 16; ++k) {
    w0c[k]  = fc0_w1[k * 16 + t];
    gcol[k] = gp[k * 16 + t];
  }
  float rr = w_readout[t];

  float cnx = coords[3 * node + 0];
  float cny = coords[3 * node + 1];
  float cnz = coords[3 * node + 2];
  int cnt = min(cursor[node], CAP);
  const int* eb = elist + (size_t)node * CAP;

  const float angc = PI_F / CUT_F;
  float acc0 = 0.f, accx = 0.f, accy = 0.f, accz = 0.f;

  for (int i = g; i < cnt; i += 8) {
    int iB = i + 4;
    bool hasB = iB < cnt;
    int sA = eb[i];
    int sB = hasB ? eb[iB] : sA;

    float pxA = coords[3 * sA + 0], pyA = coords[3 * sA + 1], pzA = coords[3 * sA + 2];
    float pxB = coords[3 * sB + 0], pyB = coords[3 * sB + 1], pzB = coords[3 * sB + 2];
    int aA = an[sA], aB = an[sB];

    float vxA = pxA - cnx, vyA = pyA - cny, vzA = pzA - cnz;
    float vxB = pxB - cnx, vyB = pyB - cny, vzB = pzB - cnz;
    float dA = sqrtf(vxA * vxA + vyA * vyA + vzA * vzA);
    float dB = sqrtf(vxB * vxB + vyB * vyB + vzB * vzB);
    float ivA = 1.0f / fmaxf(dA, 1e-9f);
    float ivB = 1.0f / fmaxf(dB, 1e-9f);
    float uxA = vxA * ivA, uyA = vyA * ivA, uzA = vzA * ivA;
    float uxB = vxB * ivB, uyB = vyB * ivB, uzB = vzB * ivB;
    float bcA = (dA < CUT_F) ? (BASIS_C * ivA) : 0.0f;
    float bcB = (dB < CUT_F) ? (BASIS_C * ivB) : 0.0f;

    // interleaved sine recurrences
    float angA = angc * dA, angB = angc * dB;
    float scA = __sinf(angA), twA = 2.0f * __cosf(angA), spA = 0.f, hAa = 0.f;
    float scB = __sinf(angB), twB = 2.0f * __cosf(angB), spB = 0.f, hBa = 0.f;
    #pragma unroll
    for (int k = 0; k < 16; ++k) {
      hAa = fmaf(scA, w0c[k], hAa);
      hBa = fmaf(scB, w0c[k], hBa);
      float snA = fmaf(twA, scA, -spA); spA = scA; scA = snA;
      float snB = fmaf(twB, scB, -spB); spB = scB; scB = snB;
    }
    float h0A = silu_fast(hAa * bcA * 0.25f);
    float h0B = silu_fast(hBa * bcB * 0.25f);

    // float2-interleaved T loads: lane t reads 8B at (a*512 + j*32 + 2t)
    const float2* tpA = (const float2*)(TI + aA * 512) + t;
    const float2* tpB = (const float2*)(TI + aB * 512) + t;
    float u0A = 0.f, u1A = 0.f, u0B = 0.f, u1B = 0.f;
    #pragma unroll
    for (int j = 0; j < 16; ++j) {
      float hjA = __shfl(h0A, base + j, 64);
      float hjB = __shfl(h0B, base + j, 64);
      float2 TA = tpA[j * 16];
      float2 TB = tpB[j * 16];
      u0A = fmaf(hjA, TA.x, u0A);
      u1A = fmaf(hjA, TA.y, u1A);
      u0B = fmaf(hjB, TB.x, u0B);
      u1B = fmaf(hjB, TB.y, u1B);
    }
    float mB = hasB ? 1.0f : 0.0f;
    acc0 += u0A + mB * u0B;
    accx = fmaf(u1A, uxA, fmaf(mB * u1B, uxB, accx));
    accy = fmaf(u1A, uyA, fmaf(mB * u1B, uyB, accy));
    accz = fmaf(u1A, uzA, fmaf(mB * u1B, uzB, accz));
  }

  // butterfly: every lane gets the 4-group totals for component t
  acc0 += __shfl_xor(acc0, 16, 64); acc0 += __shfl_xor(acc0, 32, 64);
  accx += __shfl_xor(accx, 16, 64); accx += __shfl_xor(accx, 32, 64);
  accy += __shfl_xor(accy, 16, 64); accy += __shfl_xor(accy, 32, 64);
  accz += __shfl_xor(accz, 16, 64); accz += __shfl_xor(accz, 32, 64);

  // epilogue: group 0 -> Q (G1), groups 1..3 -> P (G4), all in registers
  float srcv = (g == 0) ? acc0 * K0_F
                        : ((g == 1) ? accx : (g == 2) ? accy : accz) * K1_F;
  float o = 0.f;
  #pragma unroll
  for (int h = 0; h < 16; ++h) {
    float vh = __shfl(srcv, base + h, 64);
    o = fmaf(gcol[h], vh, o);
  }
  zbuf[(size_t)node * 64 + t * 4 + g] = o;

  // node readout: 0.25 * sum_t z0_t * r_t (group-0 lanes hold z0)
  float p = (g == 0) ? acc0 * K0_F * rr : 0.f;
  #pragma unroll
  for (int o2 = 8; o2 > 0; o2 >>= 1) p += __shfl_down(p, o2, 64);
  if (lane == 0) atomicAdd(out, p * 0.25f);
}

// ---------------------------------------------------------------------------
// Phase 2: one 16-lane group per edge (grid-stride). Lane t owns j=t.
// c_e = (INV4PI*N0/64) * sum_j h1_j * (Q_j + P_j . u); zbuf read as float4.
// ---------------------------------------------------------------------------
__global__ void __launch_bounds__(256, 4)
phase2_kernel(const int* __restrict__ ei,
              const float* __restrict__ coords,
              const float* __restrict__ fc1_w1,
              const float* __restrict__ zbuf,
              float* __restrict__ out,
              int E) {
  int t = threadIdx.x & 15;
  float w1c[16];
  #pragma unroll
  for (int k = 0; k < 16; ++k) w1c[k] = fc1_w1[k * 16 + t];

  int gid = (blockIdx.x * blockDim.x + threadIdx.x) >> 4;
  int ngroups = (gridDim.x * blockDim.x) >> 4;
  const float angc = PI_F / CUT_F;

  float c = 0.f;
  for (int e = gid; e < E; e += ngroups) {
    int s = ei[e];
    int d = ei[E + e];
    float vx = coords[3 * s + 0] - coords[3 * d + 0];
    float vy = coords[3 * s + 1] - coords[3 * d + 1];
    float vz = coords[3 * s + 2] - coords[3 * d + 2];
    float dist = sqrtf(vx * vx + vy * vy + vz * vz);
    float inv  = 1.0f / fmaxf(dist, 1e-9f);
    float ux = vx * inv, uy = vy * inv, uz = vz * inv;
    float bc = (dist < CUT_F) ? (BASIS_C * inv) : 0.0f;

    float ang = angc * dist;
    float sc = __sinf(ang);
    float tw = 2.0f * __cosf(ang);
    float sp = 0.f, acc = 0.f;
    #pragma unroll
    for (int k = 0; k < 16; ++k) {
      acc = fmaf(sc, w1c[k], acc);
      float sn = fmaf(tw, sc, -sp);
      sp = sc; sc = sn;
    }
    float h1t = silu_fast(acc * bc * 0.25f);

    float4 z = ((const float4*)(zbuf + (size_t)s * 64))[t];
    c = fmaf(h1t, fmaf(z.y, ux, fmaf(z.z, uy, fmaf(z.w, uz, z.x))), c);
  }
  c *= INV4PI_F * N0_F * (1.0f / 64.0f);
  float tot = block_reduce_sum(c);
  if (threadIdx.x == 0) atomicAdd(out, tot);
}

extern "C" void kernel_launch(void* const* d_in, const int* in_sizes, int n_in,
                              void* d_out, int out_size, void* d_ws, size_t ws_size,
                              hipStream_t stream) {
  const int*   an        = (const int*)d_in[0];
  const float* coords    = (const float*)d_in[1];
  const int*   ei        = (const int*)d_in[2];
  const float* atom_emb  = (const float*)d_in[3];
  const float* fc0_w1    = (const float*)d_in[4];
  const float* fc0_w2    = (const float*)d_in[5];
  const float* fc1_w1    = (const float*)d_in[6];
  const float* fc1_w2    = (const float*)d_in[7];
  const float* w_readout = (const float*)d_in[8];

  int N = in_sizes[0];
  int E = in_sizes[2] / 2;

  float* ws   = (float*)d_ws;
  float* zbuf = ws;                         // N*64 floats
  float* TI   = zbuf + (size_t)N * 64;      // 100*512 (float2-interleaved)
  float* G1T  = TI + NATOMS * 512;          // 256
  float* G4T  = G1T + 256;                  // 256
  int*   cursor = (int*)(G4T + 256);        // N (count)
  int*   elist  = cursor + N;               // N*CAP
  float* out = (float*)d_out;

  hipMemsetAsync(cursor, 0, (size_t)N * sizeof(int), stream);
  hipMemsetAsync(out, 0, sizeof(float), stream);

  int blk = 256;
  int ebkts = (E + blk - 1) / blk;
  setup_kernel<<<NATOMS + 1 + ebkts, blk, 0, stream>>>(
      atom_emb, fc0_w2, fc1_w2, w_readout, ei,
      TI, G1T, G4T, cursor, elist, E);

  gather_kernel<<<N, 64, 0, stream>>>(
      elist, cursor, coords, an, fc0_w1, TI, G1T, G4T, w_readout,
      zbuf, out, N);

  // 2048 blocks x 16 groups => 32768 groups, ~5 edges/group
  phase2_kernel<<<2048, blk, 0, stream>>>(ei, coords, fc1_w1, zbuf, out, E);
}

// Round 9
// 161.474 us; speedup vs baseline: 1.5785x; 1.5785x over previous
//
#include <hip/hip_runtime.h>
#include <math.h>

// EquiTritonModel: N=10000 nodes, E=160000 edges, D=32, H=16, NB=16.
// R8 -> R9: R8's 64-thr blocks regressed (preamble repeated per tiny block);
// revert to R5 geometry (256 thr, 4 nodes/block, LDS ggs, strided-dword T
// loads). NEW: edge-parallel setup precomputes packed per-edge records
// (ux,uy,uz,dist)+an[src], stored bucketed (gather) AND edge-ordered
// (phase2). Gather's serial chain elist->coords/an (2 random L2 round-trips
// per edge) becomes ONE broadcast float4 from a node-contiguous stream.

namespace {
constexpr int   NATOMS   = 100;
constexpr int   CAP      = 64;
constexpr float PI_F     = 3.14159265358979323846f;
constexpr float INV4PI_F = 0.28209479177387814f;   // 1/sqrt(4*pi)
constexpr float SQRT3_F  = 1.7320508075688772f;
constexpr float CUT_F    = 6.0f;
constexpr float BASIS_C  = 2.3094010767585034f;    // sqrt(2/6)*sqrt(16)
constexpr float N0_F     = 0.17677669529663687f;   // 1/sqrt(32)
constexpr float K0_F = INV4PI_F * N0_F * 0.0625f;
constexpr float K1_F = SQRT3_F * INV4PI_F * N0_F * 0.0625f;
}

__device__ __forceinline__ float silu_fast(float x) {
  return x / (1.0f + __expf(-x));
}

__device__ __forceinline__ float block_reduce_sum(float v) {
  #pragma unroll
  for (int o = 32; o > 0; o >>= 1) v += __shfl_down(v, o, 64);
  __shared__ float ls[8];
  int lane = threadIdx.x & 63;
  int w    = threadIdx.x >> 6;
  if (lane == 0) ls[w] = v;
  __syncthreads();
  float s = 0.f;
  if (threadIdx.x == 0) {
    int nw = (blockDim.x + 63) >> 6;
    for (int i = 0; i < nw; ++i) s += ls[i];
  }
  return s;
}

// ---------------------------------------------------------------------------
// Fused setup.
//  blocks [0,NATOMS): T0/T1[a][j][h] tables.
//  block NATOMS:      G1T/G4T [comp][hidden] (transposed).
//  blocks >NATOMS:    per-edge records: evec[e]=(ux,uy,uz,dist) edge-ordered;
//                     bucketed by dst: ebuf[d*CAP+pos]=evec, ea[..]=an[src].
// ---------------------------------------------------------------------------
__global__ void setup_kernel(const float* __restrict__ atom_emb,
                             const float* __restrict__ fc0_w2,
                             const float* __restrict__ fc1_w2,
                             const float* __restrict__ w_readout,
                             const int* __restrict__ ei,
                             const float* __restrict__ coords,
                             const int* __restrict__ an,
                             float* __restrict__ T0, float* __restrict__ T1,
                             float* __restrict__ G1T, float* __restrict__ G4T,
                             int* __restrict__ cursor,
                             float4* __restrict__ evec,
                             float4* __restrict__ ebuf,
                             int* __restrict__ ea,
                             int E) {
  int b = blockIdx.x;
  int tt = threadIdx.x;
  if (b < NATOMS) {
    int j = tt >> 4;    // hidden (h0) index
    int h = tt & 15;    // H-component
    float s0 = 0.f, s1 = 0.f;
    #pragma unroll
    for (int d = 0; d < 32; ++d) {
      float x = atom_emb[b * 32 + d];
      s0 = fmaf(x, fc0_w2[j * 1024 + d * 16 + h], s0);
      s1 = fmaf(x, fc0_w2[j * 1024 + 512 + d * 16 + h], s1);
    }
    T0[b * 256 + tt] = s0;   // [j][h]: lane h coalesced per j
    T1[b * 256 + tt] = s1;
  } else if (b == NATOMS) {
    int j = tt >> 4;
    int h = tt & 15;
    float g1 = 0.f, g4 = 0.f;
    #pragma unroll
    for (int k = 0; k < 16; ++k) {
      float r = w_readout[k];
      g1 = fmaf(fc1_w2[j * 1024 + h * 16 + k], r, g1);
      g4 = fmaf(fc1_w2[j * 1024 + 768 + h * 16 + k], r, g4);
    }
    G1T[h * 16 + j] = g1;    // [comp][hidden]: column t lane-consecutive
    G4T[h * 16 + j] = g4;
  } else {
    int e = (b - NATOMS - 1) * blockDim.x + tt;
    if (e < E) {
      int s = ei[e];
      int d = ei[E + e];
      float vx = coords[3 * s + 0] - coords[3 * d + 0];
      float vy = coords[3 * s + 1] - coords[3 * d + 1];
      float vz = coords[3 * s + 2] - coords[3 * d + 2];
      float dist = sqrtf(vx * vx + vy * vy + vz * vz);
      float inv  = 1.0f / fmaxf(dist, 1e-9f);
      float4 rec = make_float4(vx * inv, vy * inv, vz * inv, dist);
      evec[e] = rec;
      int pos = atomicAdd(&cursor[d], 1);
      if (pos < CAP) {
        ebuf[d * CAP + pos] = rec;
        ea[d * CAP + pos]   = an[s];
      }
    }
  }
}

// ---------------------------------------------------------------------------
// Phase 1 (gather): 256 thr = 4 waves = 4 nodes/block; 4 groups x 16 lanes
// per wave; lane t owns component t. Per edge: ONE broadcast float4 + int
// from node-contiguous ebuf/ea (no random access, no indirection).
// Epilogue: group 0 -> Q (G1), groups 1..3 -> Px/Py/Pz (G4);
// zbuf[node*64 + t*4 + g] (float4 per component for phase2).
// ---------------------------------------------------------------------------
__global__ void __launch_bounds__(256, 4)
gather_kernel(const float4* __restrict__ ebuf,
              const int* __restrict__ ea,
              const int* __restrict__ cursor,
              const float* __restrict__ fc0_w1,
              const float* __restrict__ T0,
              const float* __restrict__ T1,
              const float* __restrict__ G1T,
              const float* __restrict__ G4T,
              const float* __restrict__ w_readout,
              float* __restrict__ zbuf,
              float* __restrict__ out,
              int N) {
  __shared__ float ggs[512];          // [0:256)=G1T, [256:512)=G4T
  ggs[threadIdx.x]       = G1T[threadIdx.x];
  ggs[256 + threadIdx.x] = G4T[threadIdx.x];
  __syncthreads();

  int wave = threadIdx.x >> 6;
  int lane = threadIdx.x & 63;
  int g    = lane >> 4;
  int t    = lane & 15;
  int base = lane & 48;
  int node = blockIdx.x * 4 + wave;
  bool valid = node < N;

  float w0c[16];
  #pragma unroll
  for (int k = 0; k < 16; ++k) w0c[k] = fc0_w1[k * 16 + t];
  float rr = w_readout[t];

  int cnt = valid ? min(cursor[node], CAP) : 0;
  int nb  = (valid ? node : 0) * CAP;

  const float angc = PI_F / CUT_F;
  float acc0 = 0.f, accx = 0.f, accy = 0.f, accz = 0.f;

  for (int i = g; i < cnt; i += 4) {
    float4 ev = ebuf[nb + i];            // broadcast (group-uniform)
    int    a  = ea[nb + i];
    float dist = ev.w;
    float bc = (dist < CUT_F) ? (BASIS_C / fmaxf(dist, 1e-9f)) : 0.0f;

    // h0_t via sine recurrence (no cross-lane)
    float ang = angc * dist;
    float sc = __sinf(ang);
    float tw = 2.0f * __cosf(ang);
    float sp = 0.f, acc = 0.f;
    #pragma unroll
    for (int k = 0; k < 16; ++k) {
      acc = fmaf(sc, w0c[k], acc);
      float sn = fmaf(tw, sc, -sp);
      sp = sc; sc = sn;
    }
    float h0t = silu_fast(acc * bc * 0.25f);

    // coalesced strided-dword T loads (lane t at base+4t)
    const float* t0 = T0 + a * 256 + t;
    const float* t1 = T1 + a * 256 + t;
    float u0 = 0.f, u1 = 0.f;
    #pragma unroll
    for (int j = 0; j < 16; ++j) {
      float hj = __shfl(h0t, base + j, 64);
      u0 = fmaf(hj, t0[j * 16], u0);
      u1 = fmaf(hj, t1[j * 16], u1);
    }
    acc0 += u0;
    accx = fmaf(u1, ev.x, accx);
    accy = fmaf(u1, ev.y, accy);
    accz = fmaf(u1, ev.z, accz);
  }

  // butterfly: every lane gets the 4-group totals for component t
  acc0 += __shfl_xor(acc0, 16, 64); acc0 += __shfl_xor(acc0, 32, 64);
  accx += __shfl_xor(accx, 16, 64); accx += __shfl_xor(accx, 32, 64);
  accy += __shfl_xor(accy, 16, 64); accy += __shfl_xor(accy, 32, 64);
  accz += __shfl_xor(accz, 16, 64); accz += __shfl_xor(accz, 32, 64);

  // epilogue: group 0 -> Q (G1), groups 1..3 -> P (G4); conflict-free LDS
  float srcv = (g == 0) ? acc0 * K0_F
                        : ((g == 1) ? accx : (g == 2) ? accy : accz) * K1_F;
  int tofs = (g == 0) ? 0 : 256;
  float o = 0.f;
  #pragma unroll
  for (int h = 0; h < 16; ++h) {
    float vh = __shfl(srcv, base + h, 64);
    o = fmaf(ggs[tofs + h * 16 + t], vh, o);
  }
  if (valid) zbuf[(size_t)node * 64 + t * 4 + g] = o;

  // node readout partial: 0.25 * sum_t z0_t * r_t (group 0 only)
  float p = (valid && g == 0) ? acc0 * K0_F * rr : 0.f;
  float tot = block_reduce_sum(p);
  if (threadIdx.x == 0) atomicAdd(out, tot * 0.25f);
}

// ---------------------------------------------------------------------------
// Phase 2: one 16-lane group per edge (grid-stride). Lane t owns j=t.
// Loads: evec[e] (broadcast), ei[e] (broadcast), zbuf[s] (coalesced float4).
// c_e = (INV4PI*N0/64) * sum_j h1_j * (Q_j + P_j . u)
// ---------------------------------------------------------------------------
__global__ void __launch_bounds__(256, 4)
phase2_kernel(const int* __restrict__ ei,
              const float4* __restrict__ evec,
              const float* __restrict__ fc1_w1,
              const float* __restrict__ zbuf,
              float* __restrict__ out,
              int E) {
  int t = threadIdx.x & 15;
  float w1c[16];
  #pragma unroll
  for (int k = 0; k < 16; ++k) w1c[k] = fc1_w1[k * 16 + t];

  int gid = (blockIdx.x * blockDim.x + threadIdx.x) >> 4;
  int ngroups = (gridDim.x * blockDim.x) >> 4;
  const float angc = PI_F / CUT_F;

  float c = 0.f;
  for (int e = gid; e < E; e += ngroups) {
    int s = ei[e];
    float4 ev = evec[e];
    float dist = ev.w;
    float bc = (dist < CUT_F) ? (BASIS_C / fmaxf(dist, 1e-9f)) : 0.0f;

    float ang = angc * dist;
    float sc = __sinf(ang);
    float tw = 2.0f * __cosf(ang);
    float sp = 0.f, acc = 0.f;
    #pragma unroll
    for (int k = 0; k < 16; ++k) {
      acc = fmaf(sc, w1c[k], acc);
      float sn = fmaf(tw, sc, -sp);
      sp = sc; sc = sn;
    }
    float h1t = silu_fast(acc * bc * 0.25f);

    float4 z = ((const float4*)(zbuf + (size_t)s * 64))[t];
    c = fmaf(h1t, fmaf(z.y, ev.x, fmaf(z.z, ev.y, fmaf(z.w, ev.z, z.x))), c);
  }
  c *= INV4PI_F * N0_F * (1.0f / 64.0f);
  float tot = block_reduce_sum(c);
  if (threadIdx.x == 0) atomicAdd(out, tot);
}

extern "C" void kernel_launch(void* const* d_in, const int* in_sizes, int n_in,
                              void* d_out, int out_size, void* d_ws, size_t ws_size,
                              hipStream_t stream) {
  const int*   an        = (const int*)d_in[0];
  const float* coords    = (const float*)d_in[1];
  const int*   ei        = (const int*)d_in[2];
  const float* atom_emb  = (const float*)d_in[3];
  const float* fc0_w1    = (const float*)d_in[4];
  const float* fc0_w2    = (const float*)d_in[5];
  const float* fc1_w1    = (const float*)d_in[6];
  const float* fc1_w2    = (const float*)d_in[7];
  const float* w_readout = (const float*)d_in[8];

  int N = in_sizes[0];
  int E = in_sizes[2] / 2;

  float*  ws   = (float*)d_ws;
  float*  zbuf = ws;                          // N*64 f (16B-aligned: N*64%4==0)
  float4* evec = (float4*)(zbuf + (size_t)N * 64);   // E float4
  float4* ebuf = evec + E;                    // N*CAP float4
  float*  T0   = (float*)(ebuf + (size_t)N * CAP);   // 100*256
  float*  T1   = T0 + NATOMS * 256;           // 100*256
  float*  G1T  = T1 + NATOMS * 256;           // 256
  float*  G4T  = G1T + 256;                   // 256
  int*    cursor = (int*)(G4T + 256);         // N
  int*    ea     = cursor + N;                // N*CAP
  float*  out = (float*)d_out;

  hipMemsetAsync(cursor, 0, (size_t)N * sizeof(int), stream);
  hipMemsetAsync(out, 0, sizeof(float), stream);

  int blk = 256;
  int ebkts = (E + blk - 1) / blk;
  setup_kernel<<<NATOMS + 1 + ebkts, blk, 0, stream>>>(
      atom_emb, fc0_w2, fc1_w2, w_readout, ei, coords, an,
      T0, T1, G1T, G4T, cursor, evec, ebuf, ea, E);

  gather_kernel<<<(N + 3) / 4, blk, 0, stream>>>(
      ebuf, ea, cursor, fc0_w1, T0, T1, G1T, G4T, w_readout, zbuf, out, N);

  // 2048 blocks x 16 groups => 32768 groups, ~5 edges/group
  phase2_kernel<<<2048, blk, 0, stream>>>(ei, evec, fc1_w1, zbuf, out, E);
}